// Round 1
// baseline (411.896 us; speedup 1.0000x reference)
//
#include <hip/hip_runtime.h>
#include <hip/hip_fp16.h>

#define N_NODES 50000
#define N_EDGES 500000
#define NCLS 40
#define NBLK ((N_NODES + 255) / 256)   // 196
#define EBLK ((N_EDGES + 255) / 256)   // 1954

__device__ inline unsigned pack2(float a, float b) {
    __half2 h = __floats2half2_rn(a, b);
    return *(unsigned*)&h;
}
__device__ inline float2 unpack2(unsigned u) {
    __half2 h = *(__half2*)&u;
    return __half22float2(h);
}

// ---- dual histogram: in-degree (dst) and out-degree (src) ----
__global__ void hist2_k(const int* __restrict__ src, const int* __restrict__ dst,
                        int* __restrict__ cntD, int* __restrict__ cntS) {
    int e = blockIdx.x * 256 + threadIdx.x;
    if (e < N_EDGES) {
        atomicAdd(&cntD[dst[e]], 1);
        atomicAdd(&cntS[src[e]], 1);
    }
}

// ---- single-kernel scan: per-block scan + publish + parallel lookback ----
__global__ __launch_bounds__(256) void scan_k(const int* __restrict__ cnt,
                                              int* __restrict__ start,
                                              int* __restrict__ cursor,
                                              volatile int* __restrict__ bflag,
                                              volatile int* __restrict__ bval) {
    __shared__ int ls[256];
    __shared__ int sbase;
    __shared__ int ok_all;
    int b = blockIdx.x, t = threadIdx.x;
    int n = b * 256 + t;
    int v = (n < N_NODES) ? cnt[n] : 0;
    ls[t] = v;
    __syncthreads();
#pragma unroll
    for (int off = 1; off < 256; off <<= 1) {
        int u = (t >= off) ? ls[t - off] : 0;
        __syncthreads();
        ls[t] += u;
        __syncthreads();
    }
    int incl = ls[t];
    int total = ls[255];
    __syncthreads();

    if (t == 0) {
        bval[b] = total;
        __threadfence();
        bflag[b] = 1;
    }

    if (b > 0) {
        for (;;) {
            int f = (t < b) ? bflag[t] : 1;
            if (t == 0) ok_all = 1;
            __syncthreads();
            if (!f) ok_all = 0;
            __syncthreads();
            if (ok_all) break;
        }
        __threadfence();
        int pv = (t < b) ? bval[t] : 0;
        ls[t] = pv;
        __syncthreads();
#pragma unroll
        for (int off = 128; off > 0; off >>= 1) {
            if (t < off) ls[t] += ls[t + off];
            __syncthreads();
        }
        if (t == 0) sbase = ls[0];
        __syncthreads();
    } else {
        if (t == 0) sbase = 0;
        __syncthreads();
    }

    int excl = sbase + incl - v;
    if (n < N_NODES) { start[n] = excl; cursor[n] = excl; }
    if (n == 0) start[N_NODES] = N_EDGES;
}

// ---- scatter: src-sorted records carrying dst-sorted position + packed e ----
__global__ void scatter_k(const int* __restrict__ src, const int* __restrict__ dst,
                          const float* __restrict__ ef,
                          int* __restrict__ cursorD, int* __restrict__ cursorS,
                          uint4* __restrict__ recS0, uint4* __restrict__ recS1) {
    int e = blockIdx.x * 256 + threadIdx.x;
    if (e < N_EDGES) {
        int d = dst[e], s = src[e];
        int pD = atomicAdd(&cursorD[d], 1);
        int pS = atomicAdd(&cursorS[s], 1);
        float4 f0 = ((const float4*)ef)[e];
        float4 f1 = ((const float4*)ef)[N_EDGES + e];
        recS0[pS] = make_uint4((unsigned)pD, pack2(f0.x, f0.y), pack2(f0.z, f0.w), 0u);
        recS1[pS] = make_uint4((unsigned)pD, pack2(f1.x, f1.y), pack2(f1.z, f1.w), 0u);
    }
}

// ---- per-edge message from in-LDS y fragments ----
__device__ inline float4 msg_from(uint4 rec,
                                  float2 a0, float2 a1, float2 b0, float2 b1,
                                  float2 c0, float2 c1, float2 d0, float2 d1,
                                  float4 bias) {
    float2 e01 = unpack2(rec.y);
    float2 e23 = unpack2(rec.z);
    float4 z = bias;
    z.x = fmaf(e01.x, a0.x, z.x); z.y = fmaf(e01.x, a0.y, z.y);
    z.z = fmaf(e01.x, a1.x, z.z); z.w = fmaf(e01.x, a1.y, z.w);
    z.x = fmaf(e01.y, b0.x, z.x); z.y = fmaf(e01.y, b0.y, z.y);
    z.z = fmaf(e01.y, b1.x, z.z); z.w = fmaf(e01.y, b1.y, z.w);
    z.x = fmaf(e23.x, c0.x, z.x); z.y = fmaf(e23.x, c0.y, z.y);
    z.z = fmaf(e23.x, c1.x, z.z); z.w = fmaf(e23.x, c1.y, z.w);
    z.x = fmaf(e23.y, d0.x, z.x); z.y = fmaf(e23.y, d0.y, z.y);
    z.z = fmaf(e23.y, d1.x, z.z); z.w = fmaf(e23.y, d1.y, z.w);
    z.x = fmaxf(z.x, 0.f); z.y = fmaxf(z.y, 0.f);
    z.z = fmaxf(z.z, 0.f); z.w = fmaxf(z.w, 0.f);
    return z;
}

// ---- fused transform + message kernel: 64 src nodes per block ----
// phase 1: stage h tile (fp32, transposed)   phase 2: y = h@W_k -> half in LDS
// phase 3: walk own out-edges (src-sorted, streaming), write fp32 messages
// LDS: 16KB shT + 16KB sW + 32KB yL = 64KB -> 2 blocks/CU
__global__ __launch_bounds__(256) void fused_k(const float* __restrict__ hin,
                                               const float* __restrict__ W,
                                               const float* __restrict__ b,
                                               const uint4* __restrict__ recS,
                                               const int* __restrict__ startS,
                                               const int* __restrict__ cntS,
                                               float* __restrict__ mbuf) {
    __shared__ float shT[64 * 64];       // h transposed: shT[d*64 + node]
    __shared__ float sW[64 * 64];        // one k-slice of W
    __shared__ unsigned yL[64 * 128];    // half-packed y: [node][k*32 + h/2]
    int t = threadIdx.x;
    int n0 = blockIdx.x * 64;

    // phase 1: coalesced read, transposed LDS write (one-time, conflicts ok)
#pragma unroll
    for (int i = 0; i < 4; ++i) {
        int idx = t + 256 * i;        // 0..1023
        int nl = idx >> 4;            // node 0..63
        int dg = idx & 15;            // float4 slot 0..15
        int n = n0 + nl;
        float4 v = make_float4(0.f, 0.f, 0.f, 0.f);
        if (n < N_NODES) v = ((const float4*)hin)[(size_t)n * 16 + dg];
        shT[(dg * 4 + 0) * 64 + nl] = v.x;
        shT[(dg * 4 + 1) * 64 + nl] = v.y;
        shT[(dg * 4 + 2) * 64 + nl] = v.z;
        shT[(dg * 4 + 3) * 64 + nl] = v.w;
    }

    // phase 2: per k-slice GEMM into yL
    int nl2 = t & 31;
    int cg = t >> 5;                  // 0..7 col-groups of 8 cols
    int hc0 = cg * 8;
    for (int k = 0; k < 4; ++k) {
        const float4* W4 = (const float4*)(W + (size_t)k * 4096);
        float4* sW4 = (float4*)sW;
#pragma unroll
        for (int i = 0; i < 4; ++i) sW4[t + 256 * i] = W4[t + 256 * i];
        __syncthreads();              // also orders phase-1 shT writes (k==0)
        float acc0[8], acc1[8];
#pragma unroll
        for (int j = 0; j < 8; ++j) { acc0[j] = 0.f; acc1[j] = 0.f; }
        for (int d = 0; d < 64; ++d) {
            float a0 = shT[d * 64 + nl2];
            float a1 = shT[d * 64 + nl2 + 32];
            const float4* wr4 = (const float4*)&sW[d * 64 + hc0];
            float4 wa = wr4[0], wb = wr4[1];
            acc0[0] = fmaf(a0, wa.x, acc0[0]); acc1[0] = fmaf(a1, wa.x, acc1[0]);
            acc0[1] = fmaf(a0, wa.y, acc0[1]); acc1[1] = fmaf(a1, wa.y, acc1[1]);
            acc0[2] = fmaf(a0, wa.z, acc0[2]); acc1[2] = fmaf(a1, wa.z, acc1[2]);
            acc0[3] = fmaf(a0, wa.w, acc0[3]); acc1[3] = fmaf(a1, wa.w, acc1[3]);
            acc0[4] = fmaf(a0, wb.x, acc0[4]); acc1[4] = fmaf(a1, wb.x, acc1[4]);
            acc0[5] = fmaf(a0, wb.y, acc0[5]); acc1[5] = fmaf(a1, wb.y, acc1[5]);
            acc0[6] = fmaf(a0, wb.z, acc0[6]); acc1[6] = fmaf(a1, wb.z, acc1[6]);
            acc0[7] = fmaf(a0, wb.w, acc0[7]); acc1[7] = fmaf(a1, wb.w, acc1[7]);
        }
        unsigned* y0 = &yL[nl2 * 128 + k * 32 + cg * 4];
        unsigned* y1 = &yL[(nl2 + 32) * 128 + k * 32 + cg * 4];
#pragma unroll
        for (int j = 0; j < 4; ++j) {
            y0[j] = pack2(acc0[2 * j], acc0[2 * j + 1]);
            y1[j] = pack2(acc1[2 * j], acc1[2 * j + 1]);
        }
        __syncthreads();              // protect sW restage / final yL visibility
    }

    // phase 3: messages for this block's 64 src nodes
    int gi = t >> 4;
    int lane = t & 15;
    float4 bias = ((const float4*)b)[lane];
    float4* mb4 = (float4*)mbuf;
    for (int r = 0; r < 4; ++r) {
        int nl = r * 16 + gi;
        int n = n0 + nl;
        if (n >= N_NODES) continue;
        const unsigned* yr = &yL[nl * 128];
        uint2 q0 = *(const uint2*)&yr[0 * 32 + 2 * lane];
        uint2 q1 = *(const uint2*)&yr[1 * 32 + 2 * lane];
        uint2 q2 = *(const uint2*)&yr[2 * 32 + 2 * lane];
        uint2 q3 = *(const uint2*)&yr[3 * 32 + 2 * lane];
        float2 a0 = unpack2(q0.x), a1 = unpack2(q0.y);
        float2 b0 = unpack2(q1.x), b1 = unpack2(q1.y);
        float2 c0 = unpack2(q2.x), c1 = unpack2(q2.y);
        float2 d0 = unpack2(q3.x), d1 = unpack2(q3.y);
        int sS = startS[n], cS = cntS[n];
        int i = 0;
        for (; i + 2 <= cS; i += 2) {
            uint4 rA = recS[sS + i];
            uint4 rB = recS[sS + i + 1];
            float4 mA = msg_from(rA, a0, a1, b0, b1, c0, c1, d0, d1, bias);
            float4 mB = msg_from(rB, a0, a1, b0, b1, c0, c1, d0, d1, bias);
            mb4[(size_t)rA.x * 16 + lane] = mA;
            mb4[(size_t)rB.x * 16 + lane] = mB;
        }
        if (i < cS) {
            uint4 rA = recS[sS + i];
            mb4[(size_t)rA.x * 16 + lane] = msg_from(rA, a0, a1, b0, b1, c0, c1, d0, d1, bias);
        }
    }
}

// ---- streaming segment mean+relu over fp32 messages ----
__device__ inline float4 seg_mean_relu(const float* __restrict__ mbuf,
                                       int s0, int c, int lane) {
    const float4* mb = (const float4*)mbuf + (size_t)s0 * 16 + lane;
    float4 p0 = make_float4(0.f, 0.f, 0.f, 0.f);
    float4 p1 = p0, p2 = p0, p3 = p0;
    int i = 0;
    for (; i + 4 <= c; i += 4) {
        float4 v0 = mb[(size_t)(i + 0) * 16];
        float4 v1 = mb[(size_t)(i + 1) * 16];
        float4 v2 = mb[(size_t)(i + 2) * 16];
        float4 v3 = mb[(size_t)(i + 3) * 16];
        p0.x += v0.x; p0.y += v0.y; p0.z += v0.z; p0.w += v0.w;
        p1.x += v1.x; p1.y += v1.y; p1.z += v1.z; p1.w += v1.w;
        p2.x += v2.x; p2.y += v2.y; p2.z += v2.z; p2.w += v2.w;
        p3.x += v3.x; p3.y += v3.y; p3.z += v3.z; p3.w += v3.w;
    }
    for (; i < c; ++i) {
        float4 v = mb[(size_t)i * 16];
        p0.x += v.x; p0.y += v.y; p0.z += v.z; p0.w += v.w;
    }
    float inv = 1.0f / (float)(c > 1 ? c : 1);
    float4 r;
    r.x = fmaxf((p0.x + p1.x + p2.x + p3.x) * inv, 0.f);
    r.y = fmaxf((p0.y + p1.y + p2.y + p3.y) * inv, 0.f);
    r.z = fmaxf((p0.z + p1.z + p2.z + p3.z) * inv, 0.f);
    r.w = fmaxf((p0.w + p1.w + p2.w + p3.w) * inv, 0.f);
    return r;
}

// ---- layer-0 aggregate: mbuf -> hbuf (fp32) ----
__global__ __launch_bounds__(256) void agg_k(const float* __restrict__ mbuf,
                                             const int* __restrict__ startD,
                                             const int* __restrict__ cntD,
                                             float* __restrict__ hout) {
    int t = blockIdx.x * 256 + threadIdx.x;
    int g = t >> 4;
    int lane = t & 15;
    float4 r = seg_mean_relu(mbuf, startD[g], cntD[g], lane);
    ((float4*)hout)[(size_t)g * 16 + lane] = r;
}

// ---- layer-1 aggregate fused with final fc (block = 16 nodes) ----
__global__ __launch_bounds__(256) void agg_fc_k(const float* __restrict__ mbuf,
                                                const int* __restrict__ startD,
                                                const int* __restrict__ cntD,
                                                const float* __restrict__ Wfc,
                                                const float* __restrict__ bfc,
                                                float* __restrict__ out) {
    __shared__ float sh_h[16 * 65];
    __shared__ float sWfcT[NCLS * 65];   // transposed, padded
    __shared__ float sbfc[NCLS];
    int t = threadIdx.x;

    for (int i = t; i < 64 * NCLS; i += 256) {
        int j = i / NCLS;
        int c = i - j * NCLS;
        sWfcT[c * 65 + j] = Wfc[i];
    }
    if (t < NCLS) sbfc[t] = bfc[t];

    int nl = t >> 4;
    int lane = t & 15;
    int g = blockIdx.x * 16 + nl;        // grid exact: 3125*16 = 50000

    float4 r = seg_mean_relu(mbuf, startD[g], cntD[g], lane);
    sh_h[nl * 65 + lane * 4 + 0] = r.x;
    sh_h[nl * 65 + lane * 4 + 1] = r.y;
    sh_h[nl * 65 + lane * 4 + 2] = r.z;
    sh_h[nl * 65 + lane * 4 + 3] = r.w;
    __syncthreads();

    for (int item = t; item < 16 * NCLS; item += 256) {
        int rn = item / NCLS;
        int c = item - rn * NCLS;
        float acc = sbfc[c];
        const float* hr = &sh_h[rn * 65];
        const float* wc = &sWfcT[c * 65];
#pragma unroll
        for (int j = 0; j < 64; ++j) acc = fmaf(hr[j], wc[j], acc);
        out[(size_t)(blockIdx.x * 16 + rn) * NCLS + c] = acc;
    }
}

extern "C" void kernel_launch(void* const* d_in, const int* in_sizes, int n_in,
                              void* d_out, int out_size, void* d_ws, size_t ws_size,
                              hipStream_t stream) {
    const float* nf  = (const float*)d_in[0];
    const float* ef  = (const float*)d_in[1];
    const int*   src = (const int*)d_in[2];
    const int*   dst = (const int*)d_in[3];
    const float* W0  = (const float*)d_in[4];
    const float* b0  = (const float*)d_in[5];
    const float* W1  = (const float*)d_in[6];
    const float* b1  = (const float*)d_in[7];
    const float* Wfc = (const float*)d_in[8];
    const float* bfc = (const float*)d_in[9];
    float* out = (float*)d_out;

    char* ws = (char*)d_ws;
    size_t off = 0;
    auto alloc = [&](size_t bytes) -> void* {
        void* p = ws + off;
        off = (off + bytes + 255) & ~(size_t)255;
        return p;
    };
    // zeroed region: cntD | cntS | bflagD | bvalD | bflagS | bvalS
    int* zbuf    = (int*)alloc((size_t)(2 * 50176 + 1024) * 4);
    int* cntD    = zbuf;
    int* cntS    = zbuf + 50176;
    int* bflagD  = zbuf + 2 * 50176;
    int* bvalD   = bflagD + 256;
    int* bflagS  = bvalD + 256;
    int* bvalS   = bflagS + 256;
    int* startD  = (int*)alloc((size_t)(N_NODES + 4) * 4);
    int* cursorD = (int*)alloc((size_t)N_NODES * 4);
    int* startS  = (int*)alloc((size_t)(N_NODES + 4) * 4);
    int* cursorS = (int*)alloc((size_t)N_NODES * 4);
    uint4* recS0 = (uint4*)alloc((size_t)N_EDGES * 16);
    uint4* recS1 = (uint4*)alloc((size_t)N_EDGES * 16);
    float* mbuf  = (float*)alloc((size_t)N_EDGES * 64 * 4);   // 122 MiB fp32 messages
    float* hbuf  = (float*)alloc((size_t)N_NODES * 64 * 4);

    hipMemsetAsync(zbuf, 0, (size_t)(2 * 50176 + 1024) * 4, stream);

    hist2_k<<<EBLK, 256, 0, stream>>>(src, dst, cntD, cntS);
    scan_k<<<NBLK, 256, 0, stream>>>(cntD, startD, cursorD, bflagD, bvalD);
    scan_k<<<NBLK, 256, 0, stream>>>(cntS, startS, cursorS, bflagS, bvalS);
    scatter_k<<<EBLK, 256, 0, stream>>>(src, dst, ef, cursorD, cursorS, recS0, recS1);

    int fgrid = (N_NODES + 63) / 64;   // 782
    int agrid = N_NODES / 16;          // 3125, exact

    // layer 0: fused transform+message, then streaming aggregate
    fused_k<<<fgrid, 256, 0, stream>>>(nf, W0, b0, recS0, startS, cntS, mbuf);
    agg_k<<<agrid, 256, 0, stream>>>(mbuf, startD, cntD, hbuf);

    // layer 1: fused transform+message, then aggregate + classifier
    fused_k<<<fgrid, 256, 0, stream>>>(hbuf, W1, b1, recS1, startS, cntS, mbuf);
    agg_fc_k<<<agrid, 256, 0, stream>>>(mbuf, startD, cntD, Wfc, bfc, out);
}